// Round 2
// baseline (314.942 us; speedup 1.0000x reference)
//
#include <hip/hip_runtime.h>
#include <stdint.h>

typedef float floatx4 __attribute__((ext_vector_type(4)));
typedef int intx8 __attribute__((ext_vector_type(8)));

#define FP8_MAX 448.0f
#define BM 128
#define BN 128
#define BK 128
#define GX 2048   // blocks covering x in amax
#define GW 256    // blocks covering w

// ---------------------------------------------------------------- amax partials
__global__ void amax_partial(const float* __restrict__ x, long n4x,
                             const float* __restrict__ w, long n4w,
                             float* __restrict__ part) {
    const float4* p4; long n4, i0, stride;
    if (blockIdx.x < GX) {
        p4 = (const float4*)x; n4 = n4x;
        i0 = (long)blockIdx.x * blockDim.x + threadIdx.x;
        stride = (long)GX * blockDim.x;
    } else {
        p4 = (const float4*)w; n4 = n4w;
        i0 = (long)(blockIdx.x - GX) * blockDim.x + threadIdx.x;
        stride = (long)GW * blockDim.x;
    }
    float m = 0.f;
    for (long i = i0; i < n4; i += stride) {
        float4 v = p4[i];
        m = fmaxf(m, fmaxf(fmaxf(fabsf(v.x), fabsf(v.y)),
                           fmaxf(fabsf(v.z), fabsf(v.w))));
    }
    #pragma unroll
    for (int off = 32; off > 0; off >>= 1) m = fmaxf(m, __shfl_down(m, off, 64));
    __shared__ float red[4];
    if ((threadIdx.x & 63) == 0) red[threadIdx.x >> 6] = m;
    __syncthreads();
    if (threadIdx.x == 0)
        part[blockIdx.x] = fmaxf(fmaxf(red[0], red[1]), fmaxf(red[2], red[3]));
}

// ---------------------------------------------------------------- w-quant + publish scales
// Every block redundantly reduces the 9 KiB partials (trivial), so finalize_scales
// is absorbed: block 0 publishes {sx, sw, inv}; all blocks quantize w with sw.
// 256 blocks x 256 threads = 65536 threads = exactly n16w iterations.
__global__ void quantw_scales(const float* __restrict__ part,
                              const float* __restrict__ w, int4* __restrict__ wq,
                              long n16w, float* __restrict__ scales) {
    const int tid = threadIdx.x;
    float mx = 0.f, mw = 0.f;
    for (int i = tid; i < GX; i += 256) mx = fmaxf(mx, part[i]);
    for (int i = GX + tid; i < GX + GW; i += 256) mw = fmaxf(mw, part[i]);
    #pragma unroll
    for (int off = 32; off > 0; off >>= 1) {
        mx = fmaxf(mx, __shfl_down(mx, off, 64));
        mw = fmaxf(mw, __shfl_down(mw, off, 64));
    }
    __shared__ float rx[4], rw[4];
    if ((tid & 63) == 0) { rx[tid >> 6] = mx; rw[tid >> 6] = mw; }
    __syncthreads();
    const float ax = fmaxf(fmaxf(rx[0], rx[1]), fmaxf(rx[2], rx[3]));
    const float aw = fmaxf(fmaxf(rw[0], rw[1]), fmaxf(rw[2], rw[3]));
    const float sx = FP8_MAX / fmaxf(ax, 1e-12f);
    const float sw = FP8_MAX / fmaxf(aw, 1e-12f);
    if (blockIdx.x == 0 && tid == 0) {
        scales[0] = sx; scales[1] = sw; scales[2] = 1.0f / (sx * sw);
    }
    const float4* p4 = (const float4*)w;
    const long i = (long)blockIdx.x * 256 + tid;
    if (i < n16w) {
        float4 v0 = p4[i * 4 + 0];
        float4 v1 = p4[i * 4 + 1];
        float4 v2 = p4[i * 4 + 2];
        float4 v3 = p4[i * 4 + 3];
        int w0 = 0, w1 = 0, w2 = 0, w3 = 0;
        w0 = __builtin_amdgcn_cvt_pk_fp8_f32(v0.x * sw, v0.y * sw, w0, false);
        w0 = __builtin_amdgcn_cvt_pk_fp8_f32(v0.z * sw, v0.w * sw, w0, true);
        w1 = __builtin_amdgcn_cvt_pk_fp8_f32(v1.x * sw, v1.y * sw, w1, false);
        w1 = __builtin_amdgcn_cvt_pk_fp8_f32(v1.z * sw, v1.w * sw, w1, true);
        w2 = __builtin_amdgcn_cvt_pk_fp8_f32(v2.x * sw, v2.y * sw, w2, false);
        w2 = __builtin_amdgcn_cvt_pk_fp8_f32(v2.z * sw, v2.w * sw, w2, true);
        w3 = __builtin_amdgcn_cvt_pk_fp8_f32(v3.x * sw, v3.y * sw, w3, false);
        w3 = __builtin_amdgcn_cvt_pk_fp8_f32(v3.z * sw, v3.w * sw, w3, true);
        wq[i] = make_int4(w0, w1, w2, w3);
    }
}

// ---------------------------------------------------------------- fused quant-A + GEMM
// A: x [M][K] f32 (quantized to fp8 in-register during staging, scale sx).
// B: wq [N][K] fp8 via global_load_lds.  out[m][n] = (sum A*B) * inv + bias[n]
// LDS: row-major 128x128 bytes, 16B chunks XOR-swizzled: phys = log ^ (row&7).
//  - B path: global_load_lds writes linear LDS; source address pre-swizzled (rule 21).
//  - A path: reg-staged (load f32 -> cvt_pk_fp8 -> ds_write_b128 at swizzled slot),
//    which is exactly the freedom reg-staging buys: same logical layout as B.
// XCD swizzle: panel by belongs to exactly one XCD; its 8 bx-blocks are consecutive
// on that XCD -> each 512 KiB f32 A-panel fetched L3->L2 once.
__global__ __launch_bounds__(256) void gemm_fp8mx(
    const float* __restrict__ xf, const unsigned char* __restrict__ Bq,
    const float* __restrict__ bias, const float* __restrict__ scales,
    float* __restrict__ out, int M, int N, int K) {
    __shared__ __align__(16) unsigned char tA[BM * BK];
    __shared__ __align__(16) unsigned char tB[BN * BK];

    const int tid = threadIdx.x;
    const int lane = tid & 63;
    const int wave = tid >> 6;
    const int waveM = (wave & 1) * 64;
    const int waveN = (wave >> 1) * 64;

    // ---- XCD-aware bijective swizzle of the flat block id ----
    const int nbx = gridDim.x;                       // N/BN (= 8)
    const int nwg = nbx * gridDim.y;                 // 2048
    int bx = blockIdx.x, by = blockIdx.y;
    if (nbx == 8 && (nwg & 7) == 0) {
        const int f   = by * 8 + bx;
        const int per = nwg >> 3;                    // blocks per XCD
        const int sw  = (f & 7) * per + (f >> 3);    // bijective since nwg%8==0
        bx = sw & 7;
        by = sw >> 3;
    }
    const long m0 = (long)by * BM;
    const int n0 = bx * BN;

    const int srow = lane >> 3;   // 0..7 row within staging call
    const int sphys = lane & 7;   // physical 16B chunk

    const float sx = scales[0];
    const float inv = scales[2];

    floatx4 acc[4][4];
    #pragma unroll
    for (int i = 0; i < 4; ++i)
        #pragma unroll
        for (int j = 0; j < 4; ++j)
            acc[i][j] = (floatx4){0.f, 0.f, 0.f, 0.f};

    const int row16 = lane & 15;
    const int q2 = (lane >> 4) * 2;   // logical chunk base = 2*quad

    const float4* x4 = (const float4*)xf;
    const int K4 = K >> 2;

    for (int k0 = 0; k0 < K; k0 += BK) {
        __syncthreads();
        // ---- stage B: async fp8 global->LDS (unchanged path) ----
        #pragma unroll
        for (int c = 0; c < 4; ++c) {
            const int r = wave * 32 + c * 8 + srow;
            const int lc = (sphys ^ (r & 7)) * 16;   // pre-swizzled source offset
            __builtin_amdgcn_global_load_lds(
                (const __attribute__((address_space(1))) void*)(Bq + (long)(n0 + r) * K + k0 + lc),
                (__attribute__((address_space(3))) void*)&tB[r * BK + sphys * 16], 16, 0, 0);
        }
        // ---- stage A: f32 load -> fp8 cvt -> swizzled ds_write ----
        // thread t, step j covers float4s [4t + 1024j, +4) of the 128x128 tile:
        // row = (t>>3) + 32j, 16B chunk = t&7. Wave writes 8 full rows = 1 KiB
        // contiguous (a permutation within each row) -> conflict-free b128 writes.
        #pragma unroll
        for (int j = 0; j < 4; ++j) {
            const int fidx = (tid << 2) + (j << 10);
            const int row = fidx >> 5;               // 0..127
            const int c4 = fidx & 31;                // float4 col in row
            const float4* px = x4 + (m0 + row) * (long)K4 + (k0 >> 2) + c4;
            const float4 v0 = px[0];
            const float4 v1 = px[1];
            const float4 v2 = px[2];
            const float4 v3 = px[3];
            int w0 = 0, w1 = 0, w2 = 0, w3 = 0;
            w0 = __builtin_amdgcn_cvt_pk_fp8_f32(v0.x * sx, v0.y * sx, w0, false);
            w0 = __builtin_amdgcn_cvt_pk_fp8_f32(v0.z * sx, v0.w * sx, w0, true);
            w1 = __builtin_amdgcn_cvt_pk_fp8_f32(v1.x * sx, v1.y * sx, w1, false);
            w1 = __builtin_amdgcn_cvt_pk_fp8_f32(v1.z * sx, v1.w * sx, w1, true);
            w2 = __builtin_amdgcn_cvt_pk_fp8_f32(v2.x * sx, v2.y * sx, w2, false);
            w2 = __builtin_amdgcn_cvt_pk_fp8_f32(v2.z * sx, v2.w * sx, w2, true);
            w3 = __builtin_amdgcn_cvt_pk_fp8_f32(v3.x * sx, v3.y * sx, w3, false);
            w3 = __builtin_amdgcn_cvt_pk_fp8_f32(v3.z * sx, v3.w * sx, w3, true);
            const int phys = (tid & 7) ^ (row & 7);
            *(int4*)&tA[row * BK + phys * 16] = make_int4(w0, w1, w2, w3);
        }
        __syncthreads();

        intx8 af[4], bf[4];
        #pragma unroll
        for (int t = 0; t < 4; ++t) {
            const int row = waveM + t * 16 + row16;
            const int s = row & 7;
            const int4 lo = *(const int4*)&tA[row * BK + ((q2 ^ s)) * 16];
            const int4 hi = *(const int4*)&tA[row * BK + (((q2 + 1) ^ s)) * 16];
            af[t] = (intx8){lo.x, lo.y, lo.z, lo.w, hi.x, hi.y, hi.z, hi.w};
        }
        #pragma unroll
        for (int t = 0; t < 4; ++t) {
            const int row = waveN + t * 16 + row16;
            const int s = row & 7;
            const int4 lo = *(const int4*)&tB[row * BK + ((q2 ^ s)) * 16];
            const int4 hi = *(const int4*)&tB[row * BK + (((q2 + 1) ^ s)) * 16];
            bf[t] = (intx8){lo.x, lo.y, lo.z, lo.w, hi.x, hi.y, hi.z, hi.w};
        }
        #pragma unroll
        for (int mt = 0; mt < 4; ++mt)
            #pragma unroll
            for (int nt = 0; nt < 4; ++nt)
                acc[mt][nt] = __builtin_amdgcn_mfma_scale_f32_16x16x128_f8f6f4(
                    af[mt], bf[nt], acc[mt][nt], 0, 0, /*A=fp8,B=fp8*/
                    0, 127, 0, 127);                   /* unit E8M0 scales */
    }

    const int col = lane & 15;          // C/D: col = lane&15
    const int rbase4 = (lane >> 4) * 4; // row = quad*4 + reg
    #pragma unroll
    for (int nt = 0; nt < 4; ++nt) {
        const int gn = n0 + waveN + nt * 16 + col;
        const float bv = bias[gn];
        #pragma unroll
        for (int mt = 0; mt < 4; ++mt) {
            const long gm = m0 + waveM + mt * 16 + rbase4;
            float* po = out + gm * (long)N + gn;
            #pragma unroll
            for (int r = 0; r < 4; ++r)
                po[(long)r * N] = acc[mt][nt][r] * inv + bv;
        }
    }
}

// ---------------------------------------------------------------- launch
extern "C" void kernel_launch(void* const* d_in, const int* in_sizes, int n_in,
                              void* d_out, int out_size, void* d_ws, size_t ws_size,
                              hipStream_t stream) {
    const float* x = (const float*)d_in[0];
    const float* w = (const float*)d_in[1];
    const float* bias = (const float*)d_in[2];
    float* out = (float*)d_out;

    const long nx = in_sizes[0];   // M*K
    const long nw = in_sizes[1];   // N*K
    const int N = in_sizes[2];     // 1024
    const long K = nw / N;         // 1024
    const long M = nx / K;         // 32768

    unsigned char* ws = (unsigned char*)d_ws;
    unsigned char* wq = ws;                         // nw bytes fp8
    float* part = (float*)(ws + nw);                // GX+GW partial maxima
    float* scales = (float*)(ws + nw + 16384);      // {sx, sw, inv}

    amax_partial<<<GX + GW, 256, 0, stream>>>(x, nx / 4, w, nw / 4, part);
    quantw_scales<<<GW, 256, 0, stream>>>(part, w, (int4*)wq, nw / 16, scales);

    dim3 grid(N / BN, (int)(M / BM));
    gemm_fp8mx<<<grid, 256, 0, stream>>>(x, wq, bias, scales, out,
                                         (int)M, N, (int)K);
}

// Round 3
// 309.821 us; speedup vs baseline: 1.0165x; 1.0165x over previous
//
#include <hip/hip_runtime.h>
#include <stdint.h>

typedef float floatx4 __attribute__((ext_vector_type(4)));
typedef int intx8 __attribute__((ext_vector_type(8)));

#define FP8_MAX 448.0f
#define BM 128
#define BN 128
#define BK 128
#define GX 2048   // blocks covering x in amax
#define GW 256    // blocks covering w

// ---------------------------------------------------------------- amax partials
__global__ void amax_partial(const float* __restrict__ x, long n4x,
                             const float* __restrict__ w, long n4w,
                             float* __restrict__ part) {
    const float4* p4; long n4, i0, stride;
    if (blockIdx.x < GX) {
        p4 = (const float4*)x; n4 = n4x;
        i0 = (long)blockIdx.x * blockDim.x + threadIdx.x;
        stride = (long)GX * blockDim.x;
    } else {
        p4 = (const float4*)w; n4 = n4w;
        i0 = (long)(blockIdx.x - GX) * blockDim.x + threadIdx.x;
        stride = (long)GW * blockDim.x;
    }
    float m = 0.f;
    for (long i = i0; i < n4; i += stride) {
        float4 v = p4[i];
        m = fmaxf(m, fmaxf(fmaxf(fabsf(v.x), fabsf(v.y)),
                           fmaxf(fabsf(v.z), fabsf(v.w))));
    }
    #pragma unroll
    for (int off = 32; off > 0; off >>= 1) m = fmaxf(m, __shfl_down(m, off, 64));
    __shared__ float red[4];
    if ((threadIdx.x & 63) == 0) red[threadIdx.x >> 6] = m;
    __syncthreads();
    if (threadIdx.x == 0)
        part[blockIdx.x] = fmaxf(fmaxf(red[0], red[1]), fmaxf(red[2], red[3]));
}

// ---------------------------------------------------------------- w-quant + publish scales
__global__ void quantw_scales(const float* __restrict__ part,
                              const float* __restrict__ w, int4* __restrict__ wq,
                              long n16w, float* __restrict__ scales) {
    const int tid = threadIdx.x;
    float mx = 0.f, mw = 0.f;
    for (int i = tid; i < GX; i += 256) mx = fmaxf(mx, part[i]);
    for (int i = GX + tid; i < GX + GW; i += 256) mw = fmaxf(mw, part[i]);
    #pragma unroll
    for (int off = 32; off > 0; off >>= 1) {
        mx = fmaxf(mx, __shfl_down(mx, off, 64));
        mw = fmaxf(mw, __shfl_down(mw, off, 64));
    }
    __shared__ float rx[4], rw[4];
    if ((tid & 63) == 0) { rx[tid >> 6] = mx; rw[tid >> 6] = mw; }
    __syncthreads();
    const float ax = fmaxf(fmaxf(rx[0], rx[1]), fmaxf(rx[2], rx[3]));
    const float aw = fmaxf(fmaxf(rw[0], rw[1]), fmaxf(rw[2], rw[3]));
    const float sx = FP8_MAX / fmaxf(ax, 1e-12f);
    const float sw = FP8_MAX / fmaxf(aw, 1e-12f);
    if (blockIdx.x == 0 && tid == 0) {
        scales[0] = sx; scales[1] = sw; scales[2] = 1.0f / (sx * sw);
    }
    const float4* p4 = (const float4*)w;
    const long i = (long)blockIdx.x * 256 + tid;
    if (i < n16w) {
        float4 v0 = p4[i * 4 + 0];
        float4 v1 = p4[i * 4 + 1];
        float4 v2 = p4[i * 4 + 2];
        float4 v3 = p4[i * 4 + 3];
        int w0 = 0, w1 = 0, w2 = 0, w3 = 0;
        w0 = __builtin_amdgcn_cvt_pk_fp8_f32(v0.x * sw, v0.y * sw, w0, false);
        w0 = __builtin_amdgcn_cvt_pk_fp8_f32(v0.z * sw, v0.w * sw, w0, true);
        w1 = __builtin_amdgcn_cvt_pk_fp8_f32(v1.x * sw, v1.y * sw, w1, false);
        w1 = __builtin_amdgcn_cvt_pk_fp8_f32(v1.z * sw, v1.w * sw, w1, true);
        w2 = __builtin_amdgcn_cvt_pk_fp8_f32(v2.x * sw, v2.y * sw, w2, false);
        w2 = __builtin_amdgcn_cvt_pk_fp8_f32(v2.z * sw, v2.w * sw, w2, true);
        w3 = __builtin_amdgcn_cvt_pk_fp8_f32(v3.x * sw, v3.y * sw, w3, false);
        w3 = __builtin_amdgcn_cvt_pk_fp8_f32(v3.z * sw, v3.w * sw, w3, true);
        wq[i] = make_int4(w0, w1, w2, w3);
    }
}

// ---------------------------------------------------------------- fused quant-A + GEMM, pipelined
// A: x [M][K] f32 -> fp8 in-register (scale sx) -> swizzled ds_write.
// B: wq [N][K] fp8 via global_load_lds (source pre-swizzled, LDS linear).
// Pipeline (T3/T4 minimum-2-phase, reg-staged A):
//   loop k: issue B gload_lds(k); cvt+ds_write A(k) from regs; issue A(k+1)->regs;
//           s_waitcnt vmcnt(16) lgkmcnt(0)   [retires the 4 B gloads + my ds_writes;
//                                             the 16 A(k+1) loads STAY IN FLIGHT]
//           raw s_barrier; frag ds_reads + 16 MFMA; raw s_barrier.
// No vmcnt(0) drain anywhere in the main loop: A-load HBM latency (~900cy) hides
// under frag-reads + MFMA + next cvt instead of stalling every wave every K-step.
__global__ __launch_bounds__(256) void gemm_fp8mx(
    const float* __restrict__ xf, const unsigned char* __restrict__ Bq,
    const float* __restrict__ bias, const float* __restrict__ scales,
    float* __restrict__ out, int M, int N, int K) {
    __shared__ __align__(16) unsigned char tA[BM * BK];
    __shared__ __align__(16) unsigned char tB[BN * BK];

    const int tid = threadIdx.x;
    const int lane = tid & 63;
    const int wave = tid >> 6;
    const int waveM = (wave & 1) * 64;
    const int waveN = (wave >> 1) * 64;

    // ---- XCD-aware bijective swizzle of the flat block id ----
    const int nbx = gridDim.x;                       // N/BN (= 8)
    const int nwg = nbx * gridDim.y;                 // 2048
    int bx = blockIdx.x, by = blockIdx.y;
    if (nbx == 8 && (nwg & 7) == 0) {
        const int f   = by * 8 + bx;
        const int per = nwg >> 3;                    // blocks per XCD
        const int sw  = (f & 7) * per + (f >> 3);    // bijective since nwg%8==0
        bx = sw & 7;
        by = sw >> 3;
    }
    const long m0 = (long)by * BM;
    const int n0 = bx * BN;

    const int srow = lane >> 3;   // 0..7 row within staging call
    const int sphys = lane & 7;   // physical 16B chunk

    const float sx = scales[0];
    const float inv = scales[2];

    floatx4 acc[4][4];
    #pragma unroll
    for (int i = 0; i < 4; ++i)
        #pragma unroll
        for (int j = 0; j < 4; ++j)
            acc[i][j] = (floatx4){0.f, 0.f, 0.f, 0.f};

    const int row16 = lane & 15;
    const int q2 = (lane >> 4) * 2;   // logical chunk base = 2*quad

    const float4* x4 = (const float4*)xf;
    const int K4 = K >> 2;

    // Per-thread A coverage: fidx = tid*4 + j*1024; row = fidx>>5 (0..127),
    // float4 col base = (tid&7)*4, 4 consecutive float4s. Wave writes 8 full
    // rows = 1 KiB contiguous (permuted within row) -> conflict-free b128.
    const int arow0 = tid >> 3;          // + 32*j
    const int ac4   = (tid & 7) * 4;     // float4 col base
    const int aphys = tid & 7;           // 16B chunk (pre-XOR)

    // ---- prologue: prefetch A(k=0) into registers ----
    float4 pre[16];
    #pragma unroll
    for (int j = 0; j < 4; ++j) {
        const int row = arow0 + 32 * j;
        const float4* px = x4 + (m0 + row) * (long)K4 + ac4;
        pre[j * 4 + 0] = px[0];
        pre[j * 4 + 1] = px[1];
        pre[j * 4 + 2] = px[2];
        pre[j * 4 + 3] = px[3];
    }

    for (int k0 = 0; k0 < K; k0 += BK) {
        // ---- issue B: async fp8 global->LDS ----
        #pragma unroll
        for (int c = 0; c < 4; ++c) {
            const int r = wave * 32 + c * 8 + srow;
            const int lc = (sphys ^ (r & 7)) * 16;   // pre-swizzled source offset
            __builtin_amdgcn_global_load_lds(
                (const __attribute__((address_space(1))) void*)(Bq + (long)(n0 + r) * K + k0 + lc),
                (__attribute__((address_space(3))) void*)&tB[r * BK + sphys * 16], 16, 0, 0);
        }
        __builtin_amdgcn_sched_barrier(0);

        // ---- cvt A(k) regs -> fp8 -> swizzled ds_write ----
        #pragma unroll
        for (int j = 0; j < 4; ++j) {
            const float4 v0 = pre[j * 4 + 0];
            const float4 v1 = pre[j * 4 + 1];
            const float4 v2 = pre[j * 4 + 2];
            const float4 v3 = pre[j * 4 + 3];
            int w0 = 0, w1 = 0, w2 = 0, w3 = 0;
            w0 = __builtin_amdgcn_cvt_pk_fp8_f32(v0.x * sx, v0.y * sx, w0, false);
            w0 = __builtin_amdgcn_cvt_pk_fp8_f32(v0.z * sx, v0.w * sx, w0, true);
            w1 = __builtin_amdgcn_cvt_pk_fp8_f32(v1.x * sx, v1.y * sx, w1, false);
            w1 = __builtin_amdgcn_cvt_pk_fp8_f32(v1.z * sx, v1.w * sx, w1, true);
            w2 = __builtin_amdgcn_cvt_pk_fp8_f32(v2.x * sx, v2.y * sx, w2, false);
            w2 = __builtin_amdgcn_cvt_pk_fp8_f32(v2.z * sx, v2.w * sx, w2, true);
            w3 = __builtin_amdgcn_cvt_pk_fp8_f32(v3.x * sx, v3.y * sx, w3, false);
            w3 = __builtin_amdgcn_cvt_pk_fp8_f32(v3.z * sx, v3.w * sx, w3, true);
            const int row = arow0 + 32 * j;
            const int phys = aphys ^ (row & 7);
            *(int4*)&tA[row * BK + phys * 16] = make_int4(w0, w1, w2, w3);
        }
        __builtin_amdgcn_sched_barrier(0);

        // ---- issue A(k+1) prefetch (clamped on last iter: re-reads the hot
        //      current tile from L2; keeps outstanding-vmem count uniform) ----
        const int kn4 = ((k0 + BK < K) ? (k0 + BK) : k0) >> 2;
        #pragma unroll
        for (int j = 0; j < 4; ++j) {
            const int row = arow0 + 32 * j;
            const float4* px = x4 + (m0 + row) * (long)K4 + kn4 + ac4;
            pre[j * 4 + 0] = px[0];
            pre[j * 4 + 1] = px[1];
            pre[j * 4 + 2] = px[2];
            pre[j * 4 + 3] = px[3];
        }

        // Retire the 4 B gload_lds (oldest of 20 outstanding) + my ds_writes.
        // The 16 A(k+1) loads remain in flight across both barriers.
        asm volatile("s_waitcnt vmcnt(16) lgkmcnt(0)" ::: "memory");
        __builtin_amdgcn_s_barrier();
        __builtin_amdgcn_sched_barrier(0);

        // ---- frag reads (plain C++: compiler inserts counted lgkmcnt) + MFMA ----
        intx8 af[4], bf[4];
        #pragma unroll
        for (int t = 0; t < 4; ++t) {
            const int row = waveM + t * 16 + row16;
            const int s = row & 7;
            const int4 lo = *(const int4*)&tA[row * BK + ((q2 ^ s)) * 16];
            const int4 hi = *(const int4*)&tA[row * BK + (((q2 + 1) ^ s)) * 16];
            af[t] = (intx8){lo.x, lo.y, lo.z, lo.w, hi.x, hi.y, hi.z, hi.w};
        }
        #pragma unroll
        for (int t = 0; t < 4; ++t) {
            const int row = waveN + t * 16 + row16;
            const int s = row & 7;
            const int4 lo = *(const int4*)&tB[row * BK + ((q2 ^ s)) * 16];
            const int4 hi = *(const int4*)&tB[row * BK + (((q2 + 1) ^ s)) * 16];
            bf[t] = (intx8){lo.x, lo.y, lo.z, lo.w, hi.x, hi.y, hi.z, hi.w};
        }
        #pragma unroll
        for (int mt = 0; mt < 4; ++mt)
            #pragma unroll
            for (int nt = 0; nt < 4; ++nt)
                acc[mt][nt] = __builtin_amdgcn_mfma_scale_f32_16x16x128_f8f6f4(
                    af[mt], bf[nt], acc[mt][nt], 0, 0, /*A=fp8,B=fp8*/
                    0, 127, 0, 127);                   /* unit E8M0 scales */

        // All my frag ds_reads retired (MFMA operands forced lgkmcnt);
        // barrier so no wave overwrites tA/tB while others still read.
        __builtin_amdgcn_s_barrier();
        __builtin_amdgcn_sched_barrier(0);
    }

    const int col = lane & 15;          // C/D: col = lane&15
    const int rbase4 = (lane >> 4) * 4; // row = quad*4 + reg
    #pragma unroll
    for (int nt = 0; nt < 4; ++nt) {
        const int gn = n0 + waveN + nt * 16 + col;
        const float bv = bias[gn];
        #pragma unroll
        for (int mt = 0; mt < 4; ++mt) {
            const long gm = m0 + waveM + mt * 16 + rbase4;
            float* po = out + gm * (long)N + gn;
            #pragma unroll
            for (int r = 0; r < 4; ++r)
                po[(long)r * N] = acc[mt][nt][r] * inv + bv;
        }
    }
}

// ---------------------------------------------------------------- launch
extern "C" void kernel_launch(void* const* d_in, const int* in_sizes, int n_in,
                              void* d_out, int out_size, void* d_ws, size_t ws_size,
                              hipStream_t stream) {
    const float* x = (const float*)d_in[0];
    const float* w = (const float*)d_in[1];
    const float* bias = (const float*)d_in[2];
    float* out = (float*)d_out;

    const long nx = in_sizes[0];   // M*K
    const long nw = in_sizes[1];   // N*K
    const int N = in_sizes[2];     // 1024
    const long K = nw / N;         // 1024
    const long M = nx / K;         // 32768

    unsigned char* ws = (unsigned char*)d_ws;
    unsigned char* wq = ws;                         // nw bytes fp8
    float* part = (float*)(ws + nw);                // GX+GW partial maxima
    float* scales = (float*)(ws + nw + 16384);      // {sx, sw, inv}

    amax_partial<<<GX + GW, 256, 0, stream>>>(x, nx / 4, w, nw / 4, part);
    quantw_scales<<<GW, 256, 0, stream>>>(part, w, (int4*)wq, nw / 16, scales);

    dim3 grid(N / BN, (int)(M / BM));
    gemm_fp8mx<<<grid, 256, 0, stream>>>(x, wq, bias, scales, out,
                                         (int)M, N, (int)K);
}